// Round 17
// baseline (142.661 us; speedup 1.0000x reference)
//
#include <hip/hip_runtime.h>

#define CAP 64          // padded-bucket fallback capacity
#define CHUNK 4096      // edges per k_bin block
#define NBINS_MAX 1024  // supports n <= 131072
#define CAPB 2560       // records per bin region (expected ~2046, +11 sigma)
#define AGG_STRIDE 72   // bf16 elems per sagg row (144B: 16B-aligned, low bank conflict)

typedef __attribute__((ext_vector_type(8))) short bf16x8;
typedef __attribute__((ext_vector_type(4))) float f32x4;

__device__ __forceinline__ unsigned short f2bf_rne(float f) {
    unsigned u = __builtin_bit_cast(unsigned, f);
    u += 0x7FFFu + ((u >> 16) & 1u);
    return (unsigned short)(u >> 16);
}
__device__ __forceinline__ float bf2f(unsigned short h) {
    return __builtin_bit_cast(float, (unsigned)h << 16);
}

// ===================== main binned path =====================

// zero counters + (last block) pre-pack W fragments
__global__ void k_zero2(int* __restrict__ gcur, int nbins, int* __restrict__ degovf,
                        int n, int* __restrict__ ovfc,
                        const float* __restrict__ Wc, const float* __restrict__ Ws,
                        unsigned short* __restrict__ bfrag) {
    const int t = threadIdx.x;
    if (blockIdx.x == gridDim.x - 1) {
        for (int s = t; s < 2048; s += 256) {
            int lane = s & 63;
            int ct   = (s >> 6) & 3;
            int ks   = (s >> 8) & 1;
            int half = (s >> 9) & 1;
            int mat  = (s >> 10) & 1;
            const float* W = mat ? Ws : Wc;
            int d = ct * 16 + (lane & 15);
            int kbase = ks * 32 + (lane >> 4) * 8;
#pragma unroll
            for (int j = 0; j < 8; ++j) {
                float v = W[(kbase + j) * 64 + d];
                unsigned u = __builtin_bit_cast(unsigned, v);
                unsigned short hi = (unsigned short)(u >> 16);
                unsigned short elem;
                if (half == 0) {
                    elem = hi;
                } else {
                    float fh = __builtin_bit_cast(float, (unsigned)hi << 16);
                    float fl = v - fh;
                    elem = (unsigned short)(__builtin_bit_cast(unsigned, fl) >> 16);
                }
                bfrag[(size_t)s * 8 + j] = elem;
            }
        }
        return;
    }
    int i = blockIdx.x * blockDim.x + t;
    if (i < nbins) gcur[i] = 0;
    if (i < n) degovf[i] = 0;
    if (i == 0) *ovfc = 0;
}

// Bin edges by destination (128 nodes/bin).
__global__ __launch_bounds__(512) void k_bin(
    const int* __restrict__ row, const int* __restrict__ col, int e, int nbins,
    int* __restrict__ gcur, unsigned int* __restrict__ records,
    int* __restrict__ degovf, int* __restrict__ ovf, int* __restrict__ ovfc)
{
    __shared__ int hist[NBINS_MAX];
    __shared__ int lofs[NBINS_MAX];
    __shared__ int gadj[NBINS_MAX];
    __shared__ int tscan[512];
    __shared__ unsigned int stage[CHUNK];
    __shared__ unsigned short sbin[CHUNK];

    const int t = threadIdx.x;
    const int base = blockIdx.x * CHUNK;
    int cnt = e - base; if (cnt > CHUNK) cnt = CHUNK;
    if (cnt <= 0) return;

    for (int i = t; i < nbins; i += 512) hist[i] = 0;
    __syncthreads();

    for (int k = t; k < cnt; k += 512) atomicAdd(&hist[col[base + k] >> 7], 1);
    __syncthreads();

    const int b0 = t * 2;
    int h0 = (b0 < nbins) ? hist[b0] : 0;
    int h1 = (b0 + 1 < nbins) ? hist[b0 + 1] : 0;
    int s = h0 + h1;
    tscan[t] = s;
    __syncthreads();
    for (int off = 1; off < 512; off <<= 1) {
        int v = (t >= off) ? tscan[t - off] : 0;
        __syncthreads();
        tscan[t] += v;
        __syncthreads();
    }
    const int tbase = tscan[t] - s;

    if (b0 < nbins) {
        int gb = h0 ? atomicAdd(&gcur[b0], h0) : 0;
        lofs[b0] = tbase; gadj[b0] = gb - tbase;
    }
    if (b0 + 1 < nbins) {
        int lb = tbase + h0;
        int gb = h1 ? atomicAdd(&gcur[b0 + 1], h1) : 0;
        lofs[b0 + 1] = lb; gadj[b0 + 1] = gb - lb;
    }
    __syncthreads();

    for (int k = t; k < cnt; k += 512) {
        int c = col[base + k];
        int r = row[base + k];
        int b = c >> 7;
        int slot = atomicAdd(&lofs[b], 1);
        stage[slot] = ((unsigned)r << 7) | (unsigned)(c & 127);
        sbin[slot] = (unsigned short)b;
    }
    __syncthreads();

    for (int k = t; k < cnt; k += 512) {
        unsigned rec = stage[k];
        int b = sbin[k];
        int g = gadj[b] + k;
        if (g < CAPB) {
            records[(size_t)b * CAPB + g] = rec;
        } else {
            int q = atomicAdd(ovfc, 1);
            int c = (b << 7) | (int)(rec & 127u);
            ovf[2 * q]     = (int)(rec >> 7);
            ovf[2 * q + 1] = c;
            atomicAdd(&degovf[c], 1);
        }
    }
}

// per-bin dinv + scaled x -> bf16 table: xbf[r] = bf16(dinv_r * x_r)
__global__ __launch_bounds__(256) void k_xprep(
    const float* __restrict__ x, const unsigned int* __restrict__ records,
    const int* __restrict__ gcur, const int* __restrict__ degovf,
    float* __restrict__ dinv, unsigned short* __restrict__ xbf, int n)
{
    __shared__ int lh[128];
    __shared__ float sdinv[128];
    const int b = blockIdx.x, t = threadIdx.x;

    if (t < 128) lh[t] = 0;
    __syncthreads();
    int m = gcur[b]; if (m > CAPB) m = CAPB;
    const unsigned int* rb = records + (size_t)b * CAPB;
    for (int k = t; k < m; k += 256) atomicAdd(&lh[rb[k] & 127u], 1);
    __syncthreads();
    if (t < 128) {
        int node = (b << 7) + t;
        int dov = (node < n) ? degovf[node] : 0;
        float v = rsqrtf((float)(lh[t] + dov + 1));
        sdinv[t] = v;
        if (node < n) dinv[node] = v;
    }
    __syncthreads();

#pragma unroll
    for (int i = 0; i < 4; ++i) {
        int pos = t + i * 256;            // 0..1023, 8 floats each
        int node = (b << 7) + (pos >> 3);
        if (node >= n) break;
        float dv = sdinv[pos >> 3];
        const float4* xp = (const float4*)(x + (size_t)b * 8192 + (size_t)pos * 8);
        float4 f0 = xp[0], f1 = xp[1];
        uint4 u;
        u.x = (unsigned)f2bf_rne(f0.x * dv) | ((unsigned)f2bf_rne(f0.y * dv) << 16);
        u.y = (unsigned)f2bf_rne(f0.z * dv) | ((unsigned)f2bf_rne(f0.w * dv) << 16);
        u.z = (unsigned)f2bf_rne(f1.x * dv) | ((unsigned)f2bf_rne(f1.y * dv) << 16);
        u.w = (unsigned)f2bf_rne(f1.z * dv) | ((unsigned)f2bf_rne(f1.w * dv) << 16);
        *(uint4*)(xbf + (size_t)b * 8192 + (size_t)pos * 8) = u;
    }
}

// ---------------- FUSED: per-bin gather -> LDS agg -> MFMA -> out (pure store) ----
// Phase A = proven bin4 gather (half-wave uint loads, 8-deep), agg kept in LDS.
// Phase B = 8 waves x 16 rows: out = (xbf@Ws)/dinv + bias + dinv*(sagg@Wc).
__global__ __launch_bounds__(512) void k_aggemm(
    const int* __restrict__ gcur, const unsigned int* __restrict__ records,
    const unsigned short* __restrict__ xbf, const float* __restrict__ dinv,
    const unsigned short* __restrict__ bfrag, const float* __restrict__ bc,
    const float* __restrict__ bs, float* __restrict__ out, int n)
{
    // manual LDS layout; srec aliases sagg (srec dead after slist fill)
    __shared__ __align__(16) char smem[12288 + 128 * AGG_STRIDE * 2];
    int* slist            = (int*)smem;                 // 10240 B
    int* scnt             = (int*)(smem + 10240);       // 512 B
    int* sinc             = (int*)(smem + 10752);       // 512 B
    int* scur             = (int*)(smem + 11264);       // 512 B
    float* sdinv          = (float*)(smem + 11776);     // 512 B
    unsigned int* srec    = (unsigned int*)(smem + 12288);   // 10240 B (phase A only)
    unsigned short* sagg  = (unsigned short*)(smem + 12288); // 18432 B (after slist fill)

    const int b = blockIdx.x, t = threadIdx.x;
    int m = gcur[b]; if (m > CAPB) m = CAPB;

    if (t < 128) {
        scnt[t] = 0;
        int node = (b << 7) + t;
        sdinv[t] = (node < n) ? dinv[node] : 1.0f;
    }
    __syncthreads();

    for (int k = t; k < m; k += 512) {
        unsigned r = __builtin_nontemporal_load(&records[(size_t)b * CAPB + k]);
        srec[k] = r;
        atomicAdd(&scnt[r & 127u], 1);
    }
    __syncthreads();

    if (t < 128) sinc[t] = scnt[t];
    __syncthreads();
    for (int off = 1; off < 128; off <<= 1) {
        int v = 0;
        if (t < 128 && t >= off) v = sinc[t - off];
        __syncthreads();
        if (t < 128) sinc[t] += v;
        __syncthreads();
    }
    if (t < 128) scur[t] = sinc[t] - scnt[t];
    __syncthreads();

    for (int k = t; k < m; k += 512) {
        unsigned r = srec[k];
        int slot = atomicAdd(&scur[r & 127u], 1);
        slist[slot] = (int)(r & ~127u);   // row*128 = byte offset into xbf
    }
    __syncthreads();   // srec dead; sagg region live from here

    const int wave = t >> 6, lane = t & 63;
    const int h = lane >> 5;
    const char* ybl = (const char*)xbf + ((lane & 31) << 2);

    for (int i = wave; i < 128; i += 8) {
        int node = (b << 7) + i;
        if (node >= n) break;
        int cnt = scnt[i];
        int beg = sinc[i] - cnt;
        float ax0=0.f,ax1=0.f,ax2=0.f,ax3=0.f,ax4=0.f,ax5=0.f,ax6=0.f,ax7=0.f;
        float ay0=0.f,ay1=0.f,ay2=0.f,ay3=0.f,ay4=0.f,ay5=0.f,ay6=0.f,ay7=0.f;
        int k = 0;
        for (; k + 16 <= cnt; k += 16) {
            int o0 = slist[beg + k + 0  + h];
            int o1 = slist[beg + k + 2  + h];
            int o2 = slist[beg + k + 4  + h];
            int o3 = slist[beg + k + 6  + h];
            int o4 = slist[beg + k + 8  + h];
            int o5 = slist[beg + k + 10 + h];
            int o6 = slist[beg + k + 12 + h];
            int o7 = slist[beg + k + 14 + h];
            unsigned v0 = *(const unsigned*)(ybl + o0);
            unsigned v1 = *(const unsigned*)(ybl + o1);
            unsigned v2 = *(const unsigned*)(ybl + o2);
            unsigned v3 = *(const unsigned*)(ybl + o3);
            unsigned v4 = *(const unsigned*)(ybl + o4);
            unsigned v5 = *(const unsigned*)(ybl + o5);
            unsigned v6 = *(const unsigned*)(ybl + o6);
            unsigned v7 = *(const unsigned*)(ybl + o7);
            ax0 += bf2f((unsigned short)v0); ay0 += bf2f((unsigned short)(v0 >> 16));
            ax1 += bf2f((unsigned short)v1); ay1 += bf2f((unsigned short)(v1 >> 16));
            ax2 += bf2f((unsigned short)v2); ay2 += bf2f((unsigned short)(v2 >> 16));
            ax3 += bf2f((unsigned short)v3); ay3 += bf2f((unsigned short)(v3 >> 16));
            ax4 += bf2f((unsigned short)v4); ay4 += bf2f((unsigned short)(v4 >> 16));
            ax5 += bf2f((unsigned short)v5); ay5 += bf2f((unsigned short)(v5 >> 16));
            ax6 += bf2f((unsigned short)v6); ay6 += bf2f((unsigned short)(v6 >> 16));
            ax7 += bf2f((unsigned short)v7); ay7 += bf2f((unsigned short)(v7 >> 16));
        }
        for (; k + 2 <= cnt; k += 2) {
            int o = slist[beg + k + h];
            unsigned v = *(const unsigned*)(ybl + o);
            ax0 += bf2f((unsigned short)v);
            ay0 += bf2f((unsigned short)(v >> 16));
        }
        if (k < cnt && h == 0) {
            int o = slist[beg + k];
            unsigned v = *(const unsigned*)(ybl + o);
            ax0 += bf2f((unsigned short)v);
            ay0 += bf2f((unsigned short)(v >> 16));
        }
        float sx = ((ax0+ax1)+(ax2+ax3)) + ((ax4+ax5)+(ax6+ax7));
        float sy = ((ay0+ay1)+(ay2+ay3)) + ((ay4+ay5)+(ay6+ay7));
        sx += __shfl_down(sx, 32);
        sy += __shfl_down(sy, 32);
        if (h == 0) {
            unsigned own = *(const unsigned*)((const char*)xbf + ((size_t)node << 7) + ((lane & 31) << 2));
            sx += bf2f((unsigned short)own);
            sy += bf2f((unsigned short)(own >> 16));
            unsigned pk = (unsigned)f2bf_rne(sx) | ((unsigned)f2bf_rne(sy) << 16);
            ((unsigned*)sagg)[i * (AGG_STRIDE / 2) + (lane & 31)] = pk;
        }
    }
    __syncthreads();

    // ---------- phase B: GEMM from LDS agg + global xbf ----------
    const int lrow0 = wave * 16;
    const int grow0 = (b << 7) + lrow0;
    if (grow0 >= n) return;

    const int arow = lane & 15;
    const int kgrp = lane >> 4;
    int lrow = lrow0 + arow;
    int grow = (b << 7) + lrow; if (grow >= n) grow = n - 1;

    bf16x8 a_x[2], a_g[2];
#pragma unroll
    for (int ks = 0; ks < 2; ++ks) {
        a_x[ks] = *(const bf16x8*)(xbf + (size_t)grow * 64 + ks * 32 + kgrp * 8);
        a_g[ks] = *(const bf16x8*)(sagg + lrow * AGG_STRIDE + ks * 32 + kgrp * 8);
    }

    const int dcol = lane & 15;
    const int rb2 = (lane >> 4) * 4;

#pragma unroll
    for (int ct = 0; ct < 4; ++ct) {
        f32x4 accC = (f32x4){0.f, 0.f, 0.f, 0.f};
        f32x4 accS = (f32x4){0.f, 0.f, 0.f, 0.f};
#pragma unroll
        for (int ks = 0; ks < 2; ++ks) {
            const bf16x8 ch = *(const bf16x8*)(bfrag + ((size_t)(((0 * 2 + ks) * 4 + ct) * 64 + lane)) * 8);
            const bf16x8 cl = *(const bf16x8*)(bfrag + ((size_t)(((1 * 2 + ks) * 4 + ct) * 64 + lane)) * 8);
            accC = __builtin_amdgcn_mfma_f32_16x16x32_bf16(a_g[ks], ch, accC, 0, 0, 0);
            accC = __builtin_amdgcn_mfma_f32_16x16x32_bf16(a_g[ks], cl, accC, 0, 0, 0);
            const bf16x8 sh = *(const bf16x8*)(bfrag + ((size_t)(((2 * 2 + ks) * 4 + ct) * 64 + lane)) * 8);
            const bf16x8 sl = *(const bf16x8*)(bfrag + ((size_t)(((3 * 2 + ks) * 4 + ct) * 64 + lane)) * 8);
            accS = __builtin_amdgcn_mfma_f32_16x16x32_bf16(a_x[ks], sh, accS, 0, 0, 0);
            accS = __builtin_amdgcn_mfma_f32_16x16x32_bf16(a_x[ks], sl, accS, 0, 0, 0);
        }
        int d = ct * 16 + dcol;
        float bias = bc[d] + bs[d];
#pragma unroll
        for (int reg = 0; reg < 4; ++reg) {
            int lr = lrow0 + rb2 + reg;
            int row = (b << 7) + lr;
            if (row < n) {
                float dv = sdinv[lr];
                out[(size_t)row * 64 + d] = accS[reg] / dv + bias + dv * accC[reg];
            }
        }
    }
}

// overflow edges: out[c] += dinv_c * (xbf[r] @ Wc)  (after gemm; m expected 0)
__global__ void k_ovf3(const int* __restrict__ ovfc, const int* __restrict__ ovf,
                       const float* __restrict__ dinv, const unsigned short* __restrict__ xbf,
                       const float* __restrict__ Wc, float* __restrict__ out) {
    int m = *ovfc;
    int wid = (blockIdx.x * blockDim.x + threadIdx.x) >> 6;
    int lane = threadIdx.x & 63;
    int nw = (gridDim.x * blockDim.x) >> 6;
    for (int q = wid; q < m; q += nw) {
        int r = ovf[2 * q], c = ovf[2 * q + 1];
        float acc = 0.f;
        for (int k = 0; k < 64; ++k)
            acc += bf2f(xbf[(size_t)r * 64 + k]) * Wc[k * 64 + lane];
        unsafeAtomicAdd(out + (size_t)c * 64 + lane, dinv[c] * acc);
    }
}

// ===================== padded-bucket fallback (round-3 proven) =====================

__global__ void k_init(int* __restrict__ cnt, int* __restrict__ ovf_cnt, int n) {
    int i = blockIdx.x * blockDim.x + threadIdx.x;
    if (i < n) cnt[i] = 0;
    if (i == 0) *ovf_cnt = 0;
}

__global__ void k_fill_pad(const int* __restrict__ row, const int* __restrict__ col,
                           int* __restrict__ cnt, int* __restrict__ bucket,
                           int* __restrict__ ovf, int* __restrict__ ovf_cnt, int e) {
    int i = blockIdx.x * blockDim.x + threadIdx.x;
    if (i >= e) return;
    int c = col[i];
    int p = atomicAdd(&cnt[c], 1);
    if (p < CAP) bucket[(size_t)c * CAP + p] = row[i];
    else { int q = atomicAdd(ovf_cnt, 1); ovf[q] = i; }
}

__global__ __launch_bounds__(256) void k_gemm(
    const float* __restrict__ x, const float* __restrict__ Wc,
    const float* __restrict__ bc, const float* __restrict__ Ws,
    const float* __restrict__ bs, const int* __restrict__ deg, int add,
    float* __restrict__ dinv, float* __restrict__ y,
    float* __restrict__ out, int n)
{
    __shared__ __align__(16) float sWc[64 * 64];
    __shared__ __align__(16) float sWs[64 * 64];
    __shared__ __align__(16) float sx[64 * 64];
    const int t = threadIdx.x;

    for (int i = t; i < 1024; i += 256) {
        ((float4*)sWc)[i] = ((const float4*)Wc)[i];
        ((float4*)sWs)[i] = ((const float4*)Ws)[i];
    }
    const int row0 = blockIdx.x * 64;
    int nrows = n - row0; if (nrows > 64) nrows = 64;
    for (int i = t; i < nrows * 16; i += 256) {
        ((float4*)sx)[i] = ((const float4*)(x + (size_t)row0 * 64))[i];
    }
    __syncthreads();

    const int d = t & 63;
    const int g = t >> 6;

    float wcr[64], wsr[64];
#pragma unroll
    for (int k = 0; k < 64; ++k) { wcr[k] = sWc[k * 64 + d]; wsr[k] = sWs[k * 64 + d]; }

    const float bcd = bc[d], bsd = bs[d];

    for (int rr = g * 16; rr < (g + 1) * 16; ++rr) {
        if (rr >= nrows) break;
        float accC = 0.f, accS = 0.f;
        const float4* xv4 = (const float4*)(sx + rr * 64);
#pragma unroll
        for (int q = 0; q < 16; ++q) {
            float4 xv = xv4[q];
            accC += xv.x*wcr[4*q+0] + xv.y*wcr[4*q+1] + xv.z*wcr[4*q+2] + xv.w*wcr[4*q+3];
            accS += xv.x*wsr[4*q+0] + xv.y*wsr[4*q+1] + xv.z*wsr[4*q+2] + xv.w*wsr[4*q+3];
        }
        const int r = row0 + rr;
        const float di = rsqrtf((float)(deg[r] + add));
        if (d == 0) dinv[r] = di;
        const float yv = accC * di;
        y[(size_t)r * 64 + d] = yv;
        out[(size_t)r * 64 + d] = accS + bsd + bcd + di * yv;
    }
}

__global__ __launch_bounds__(256) void k_gather_pad(
    const int* __restrict__ cnt, const int* __restrict__ bucket,
    const float* __restrict__ y, float* __restrict__ out, int n)
{
    const int node = blockIdx.x * 4 + (threadIdx.x >> 6);
    if (node >= n) return;
    const int lane = threadIdx.x & 63;
    int m = cnt[node];
    const float di = rsqrtf((float)(m + 1));
    if (m > CAP) m = CAP;
    if (m == 0) return;

    int rl = (lane < m) ? bucket[(size_t)node * CAP + lane] : 0;

    float a0=0.f,a1=0.f,a2=0.f,a3=0.f,a4=0.f,a5=0.f,a6=0.f,a7=0.f;
    int k = 0;
    for (; k + 8 <= m; k += 8) {
        int r0=__shfl(rl,k+0), r1=__shfl(rl,k+1), r2=__shfl(rl,k+2), r3=__shfl(rl,k+3);
        int r4=__shfl(rl,k+4), r5=__shfl(rl,k+5), r6=__shfl(rl,k+6), r7=__shfl(rl,k+7);
        a0 += y[(size_t)r0*64 + lane];
        a1 += y[(size_t)r1*64 + lane];
        a2 += y[(size_t)r2*64 + lane];
        a3 += y[(size_t)r3*64 + lane];
        a4 += y[(size_t)r4*64 + lane];
        a5 += y[(size_t)r5*64 + lane];
        a6 += y[(size_t)r6*64 + lane];
        a7 += y[(size_t)r7*64 + lane];
    }
    for (; k + 2 <= m; k += 2) {
        int r0=__shfl(rl,k+0), r1=__shfl(rl,k+1);
        a0 += y[(size_t)r0*64 + lane];
        a1 += y[(size_t)r1*64 + lane];
    }
    if (k < m) { int r0=__shfl(rl,k); a0 += y[(size_t)r0*64 + lane]; }

    float acc = ((a0+a1)+(a2+a3)) + ((a4+a5)+(a6+a7));
    out[(size_t)node*64 + lane] += di * acc;
}

__global__ void k_ovf_idx(const int* __restrict__ ovf_cnt, const int* __restrict__ ovf,
                          const int* __restrict__ row, const int* __restrict__ col,
                          const float* __restrict__ dinv, const float* __restrict__ y,
                          float* __restrict__ out) {
    int m = *ovf_cnt;
    long long total = (long long)m * 16;
    for (long long idx = blockIdx.x*blockDim.x+threadIdx.x; idx < total;
         idx += (long long)gridDim.x*blockDim.x) {
        int ei = ovf[idx >> 4];
        int j = (int)(idx & 15);
        int r = row[ei], c = col[ei];
        float s = dinv[c];
        float4 v = ((const float4*)y)[(size_t)r*16 + j];
        float* o = out + (size_t)c*64 + (j<<2);
        unsafeAtomicAdd(o+0, s*v.x);
        unsafeAtomicAdd(o+1, s*v.y);
        unsafeAtomicAdd(o+2, s*v.z);
        unsafeAtomicAdd(o+3, s*v.w);
    }
}

__global__ void k_deg_init(int* __restrict__ deg, int n) {
    int i = blockIdx.x * blockDim.x + threadIdx.x;
    if (i < n) deg[i] = 1;
}

__global__ void k_deg_count(const int* __restrict__ col, int* __restrict__ deg, int e) {
    int i = blockIdx.x * blockDim.x + threadIdx.x;
    if (i < e) atomicAdd(&deg[col[i]], 1);
}

__global__ __launch_bounds__(256) void k_scatter(
    const int* __restrict__ row, const int* __restrict__ col,
    const float* __restrict__ dinv, const float* __restrict__ y,
    float* __restrict__ out, int e)
{
    int idx = blockIdx.x * blockDim.x + threadIdx.x;
    int eidx = idx >> 4;
    if (eidx >= e) return;
    int j = idx & 15;
    int r = row[eidx];
    int c = col[eidx];
    float s = dinv[c];
    float4 v = ((const float4*)y)[(size_t)r * 16 + j];
    float* o = out + (size_t)c * 64 + (j << 2);
    unsafeAtomicAdd(o + 0, s * v.x);
    unsafeAtomicAdd(o + 1, s * v.y);
    unsafeAtomicAdd(o + 2, s * v.z);
    unsafeAtomicAdd(o + 3, s * v.w);
}

extern "C" void kernel_launch(void* const* d_in, const int* in_sizes, int n_in,
                              void* d_out, int out_size, void* d_ws, size_t ws_size,
                              hipStream_t stream) {
    const float* x  = (const float*)d_in[0];
    const int*   ei = (const int*)d_in[1];
    const float* Wc = (const float*)d_in[2];
    const float* bc = (const float*)d_in[3];
    const float* Ws = (const float*)d_in[4];
    const float* bs = (const float*)d_in[5];
    float* out = (float*)d_out;

    const int n = in_sizes[0] / 64;
    const int e = in_sizes[1] / 2;
    const int* rowi = ei;
    const int* coli = ei + e;

    auto align = [](size_t v) { return (v + 255) & ~(size_t)255; };
    char* ws = (char*)d_ws;
    const int nbins = (n + 127) >> 7;

    // ---- aggregate-first layout: xbf is a bf16 n*128B table ----
    size_t m_dinv = 0;
    size_t m_xbf  = align(m_dinv + (size_t)n * 4);
    size_t m_gcur = align(m_xbf  + (size_t)n * 128);
    size_t m_rec  = align(m_gcur + (size_t)nbins * 4);
    size_t m_dov  = align(m_rec  + (size_t)nbins * CAPB * 4);
    size_t m_ovf  = align(m_dov  + (size_t)n * 4);
    size_t m_ovfc = align(m_ovf  + (size_t)e * 8);
    size_t m_bfr  = align(m_ovfc + 256);
    size_t m_tot  = m_bfr + 32768;

    // ---- padded-bucket layout ----
    size_t p_cnt  = 0;
    size_t p_dinv = align(p_cnt  + (size_t)n * 4);
    size_t p_y    = align(p_dinv + (size_t)n * 4);
    size_t p_bkt  = align(p_y    + (size_t)n * 256);
    size_t p_ovf  = align(p_bkt  + (size_t)n * CAP * 4);
    size_t p_ovfc = align(p_ovf  + (size_t)e * 4);
    size_t p_tot  = p_ovfc + 256;

    if (nbins <= NBINS_MAX && m_tot <= ws_size) {
        float* dinv = (float*)(ws + m_dinv);
        unsigned short* xbf = (unsigned short*)(ws + m_xbf);
        int*   gcur = (int*)(ws + m_gcur);
        unsigned int* rec = (unsigned int*)(ws + m_rec);
        int*   dov  = (int*)(ws + m_dov);
        int*   ovf  = (int*)(ws + m_ovf);
        int*   ovfc = (int*)(ws + m_ovfc);
        unsigned short* bfrag = (unsigned short*)(ws + m_bfr);

        int zmax = (n > nbins) ? n : nbins;
        k_zero2<<<(zmax + 255) / 256 + 1, 256, 0, stream>>>(gcur, nbins, dov, n, ovfc,
                                                            Wc, Ws, bfrag);
        k_bin<<<(e + CHUNK - 1) / CHUNK, 512, 0, stream>>>(rowi, coli, e, nbins,
                                                           gcur, rec, dov, ovf, ovfc);
        k_xprep<<<nbins, 256, 0, stream>>>(x, rec, gcur, dov, dinv, xbf, n);
        k_aggemm<<<nbins, 512, 0, stream>>>(gcur, rec, xbf, dinv, bfrag, bc, bs, out, n);
        k_ovf3<<<64, 256, 0, stream>>>(ovfc, ovf, dinv, xbf, Wc, out);
    } else if (p_tot <= ws_size) {
        int*   cnt    = (int*)(ws + p_cnt);
        float* dinv   = (float*)(ws + p_dinv);
        float* y      = (float*)(ws + p_y);
        int*   bucket = (int*)(ws + p_bkt);
        int*   ovf    = (int*)(ws + p_ovf);
        int*   ovfc   = (int*)(ws + p_ovfc);

        k_init<<<(n + 255) / 256, 256, 0, stream>>>(cnt, ovfc, n);
        k_fill_pad<<<(e + 255) / 256, 256, 0, stream>>>(rowi, coli, cnt, bucket, ovf, ovfc, e);
        k_gemm<<<(n + 63) / 64, 256, 0, stream>>>(x, Wc, bc, Ws, bs, cnt, 1, dinv, y, out, n);
        k_gather_pad<<<(n + 3) / 4, 256, 0, stream>>>(cnt, bucket, y, out, n);
        k_ovf_idx<<<64, 256, 0, stream>>>(ovfc, ovf, rowi, coli, dinv, y, out);
    } else {
        size_t a_deg  = 0;
        size_t a_dinv = align(a_deg  + (size_t)n * 4);
        size_t a_y    = align(a_dinv + (size_t)n * 4);
        int*   deg  = (int*)(ws + a_deg);
        float* dinv = (float*)(ws + a_dinv);
        float* y    = (float*)(ws + a_y);
        k_deg_init<<<(n + 255) / 256, 256, 0, stream>>>(deg, n);
        k_deg_count<<<(e + 255) / 256, 256, 0, stream>>>(coli, deg, e);
        k_gemm<<<(n + 63) / 64, 256, 0, stream>>>(x, Wc, bc, Ws, bs, deg, 0, dinv, y, out, n);
        long long tot = (long long)e * 16;
        k_scatter<<<(int)((tot + 255) / 256), 256, 0, stream>>>(rowi, coli, dinv, y, out, e);
    }
}

// Round 18
// 113.655 us; speedup vs baseline: 1.2552x; 1.2552x over previous
//
#include <hip/hip_runtime.h>

#define CAP 64          // padded-bucket fallback capacity
#define CHUNK 4096      // edges per k_bin block
#define NBINS_MAX 1024  // supports n <= 131072
#define CAPB 2560       // records per bin region (expected ~2046, +11 sigma)

typedef __attribute__((ext_vector_type(8))) short bf16x8;
typedef __attribute__((ext_vector_type(4))) float f32x4;

__device__ __forceinline__ unsigned short f2bf_rne(float f) {
    unsigned u = __builtin_bit_cast(unsigned, f);
    u += 0x7FFFu + ((u >> 16) & 1u);
    return (unsigned short)(u >> 16);
}
__device__ __forceinline__ float bf2f(unsigned short h) {
    return __builtin_bit_cast(float, (unsigned)h << 16);
}

// ===================== main binned path =====================

// zero counters + (last block) pre-pack W fragments
__global__ void k_zero2(int* __restrict__ gcur, int nbins, int* __restrict__ degovf,
                        int n, int* __restrict__ ovfc,
                        const float* __restrict__ Wc, const float* __restrict__ Ws,
                        unsigned short* __restrict__ bfrag) {
    const int t = threadIdx.x;
    if (blockIdx.x == gridDim.x - 1) {
        for (int s = t; s < 2048; s += 256) {
            int lane = s & 63;
            int ct   = (s >> 6) & 3;
            int ks   = (s >> 8) & 1;
            int half = (s >> 9) & 1;
            int mat  = (s >> 10) & 1;
            const float* W = mat ? Ws : Wc;
            int d = ct * 16 + (lane & 15);
            int kbase = ks * 32 + (lane >> 4) * 8;
#pragma unroll
            for (int j = 0; j < 8; ++j) {
                float v = W[(kbase + j) * 64 + d];
                unsigned u = __builtin_bit_cast(unsigned, v);
                unsigned short hi = (unsigned short)(u >> 16);
                unsigned short elem;
                if (half == 0) {
                    elem = hi;
                } else {
                    float fh = __builtin_bit_cast(float, (unsigned)hi << 16);
                    float fl = v - fh;
                    elem = (unsigned short)(__builtin_bit_cast(unsigned, fl) >> 16);
                }
                bfrag[(size_t)s * 8 + j] = elem;
            }
        }
        return;
    }
    int i = blockIdx.x * blockDim.x + t;
    if (i < nbins) gcur[i] = 0;
    if (i < n) degovf[i] = 0;
    if (i == 0) *ovfc = 0;
}

// Bin edges by destination (128 nodes/bin).
__global__ __launch_bounds__(512) void k_bin(
    const int* __restrict__ row, const int* __restrict__ col, int e, int nbins,
    int* __restrict__ gcur, unsigned int* __restrict__ records,
    int* __restrict__ degovf, int* __restrict__ ovf, int* __restrict__ ovfc)
{
    __shared__ int hist[NBINS_MAX];
    __shared__ int lofs[NBINS_MAX];
    __shared__ int gadj[NBINS_MAX];
    __shared__ int tscan[512];
    __shared__ unsigned int stage[CHUNK];
    __shared__ unsigned short sbin[CHUNK];

    const int t = threadIdx.x;
    const int base = blockIdx.x * CHUNK;
    int cnt = e - base; if (cnt > CHUNK) cnt = CHUNK;
    if (cnt <= 0) return;

    for (int i = t; i < nbins; i += 512) hist[i] = 0;
    __syncthreads();

    for (int k = t; k < cnt; k += 512) atomicAdd(&hist[col[base + k] >> 7], 1);
    __syncthreads();

    const int b0 = t * 2;
    int h0 = (b0 < nbins) ? hist[b0] : 0;
    int h1 = (b0 + 1 < nbins) ? hist[b0 + 1] : 0;
    int s = h0 + h1;
    tscan[t] = s;
    __syncthreads();
    for (int off = 1; off < 512; off <<= 1) {
        int v = (t >= off) ? tscan[t - off] : 0;
        __syncthreads();
        tscan[t] += v;
        __syncthreads();
    }
    const int tbase = tscan[t] - s;

    if (b0 < nbins) {
        int gb = h0 ? atomicAdd(&gcur[b0], h0) : 0;
        lofs[b0] = tbase; gadj[b0] = gb - tbase;
    }
    if (b0 + 1 < nbins) {
        int lb = tbase + h0;
        int gb = h1 ? atomicAdd(&gcur[b0 + 1], h1) : 0;
        lofs[b0 + 1] = lb; gadj[b0 + 1] = gb - lb;
    }
    __syncthreads();

    for (int k = t; k < cnt; k += 512) {
        int c = col[base + k];
        int r = row[base + k];
        int b = c >> 7;
        int slot = atomicAdd(&lofs[b], 1);
        stage[slot] = ((unsigned)r << 7) | (unsigned)(c & 127);
        sbin[slot] = (unsigned short)b;
    }
    __syncthreads();

    for (int k = t; k < cnt; k += 512) {
        unsigned rec = stage[k];
        int b = sbin[k];
        int g = gadj[b] + k;
        if (g < CAPB) {
            records[(size_t)b * CAPB + g] = rec;
        } else {
            int q = atomicAdd(ovfc, 1);
            int c = (b << 7) | (int)(rec & 127u);
            ovf[2 * q]     = (int)(rec >> 7);
            ovf[2 * q + 1] = c;
            atomicAdd(&degovf[c], 1);
        }
    }
}

// ---------------- GEMM v6: fused per-bin dinv + MFMA 2-term bf16 split ----------
__global__ __launch_bounds__(256) void k_gemm6(
    const float* __restrict__ x, const unsigned short* __restrict__ bfrag,
    const float* __restrict__ bc, const float* __restrict__ bs,
    const unsigned int* __restrict__ records, const int* __restrict__ gcur,
    const int* __restrict__ degovf, float* __restrict__ dinv,
    unsigned short* __restrict__ ybf, float* __restrict__ out, int n)
{
    __shared__ int lh[128];
    __shared__ float sdinv[128];

    const int b = blockIdx.x;
    const int t = threadIdx.x;

    if (t < 128) lh[t] = 0;
    __syncthreads();
    int m = gcur[b]; if (m > CAPB) m = CAPB;
    const unsigned int* rb = records + (size_t)b * CAPB;
    for (int k = t; k < m; k += 256) atomicAdd(&lh[rb[k] & 127u], 1);
    __syncthreads();
    if (t < 128) {
        int node = (b << 7) + t;
        int dov = (node < n) ? degovf[node] : 0;
        float v = rsqrtf((float)(lh[t] + dov + 1));
        sdinv[t] = v;
        if (node < n) dinv[node] = v;
    }
    __syncthreads();

    const int lane = t & 63;
    const int wid = t >> 6;
    const int rt0 = b * 128 + wid * 32;
    const int lbase = wid * 32;
    if (rt0 >= n) return;

    const int arow = lane & 15;
    const int kgrp = lane >> 4;

    bf16x8 a_hi[2][2];
#pragma unroll
    for (int rt = 0; rt < 2; ++rt) {
        int row = rt0 + rt * 16 + arow;
        if (row >= n) row = n - 1;
        const float* xp = x + (size_t)row * 64 + kgrp * 8;
#pragma unroll
        for (int ks = 0; ks < 2; ++ks) {
            float4 f0 = *(const float4*)(xp + ks * 32);
            float4 f1 = *(const float4*)(xp + ks * 32 + 4);
            float f[8] = {f0.x, f0.y, f0.z, f0.w, f1.x, f1.y, f1.z, f1.w};
            bf16x8 h;
#pragma unroll
            for (int j = 0; j < 8; ++j) {
                unsigned u = __builtin_bit_cast(unsigned, f[j]);
                h[j] = (short)(unsigned short)(u >> 16);   // truncation
            }
            a_hi[rt][ks] = h;
        }
    }

    f32x4 acc[2][2][4];
#pragma unroll
    for (int mm = 0; mm < 2; ++mm)
#pragma unroll
        for (int rt = 0; rt < 2; ++rt)
#pragma unroll
            for (int ct = 0; ct < 4; ++ct)
                acc[mm][rt][ct] = (f32x4){0.f, 0.f, 0.f, 0.f};

#pragma unroll
    for (int mat = 0; mat < 2; ++mat) {
#pragma unroll
        for (int ks = 0; ks < 2; ++ks) {
#pragma unroll
            for (int ct = 0; ct < 4; ++ct) {
                const bf16x8 bh = *(const bf16x8*)(bfrag + ((size_t)((((mat * 2 + 0) * 2 + ks) * 4 + ct) * 64 + lane)) * 8);
                const bf16x8 bl = *(const bf16x8*)(bfrag + ((size_t)((((mat * 2 + 1) * 2 + ks) * 4 + ct) * 64 + lane)) * 8);
#pragma unroll
                for (int rt = 0; rt < 2; ++rt) {
                    acc[mat][rt][ct] = __builtin_amdgcn_mfma_f32_16x16x32_bf16(a_hi[rt][ks], bh, acc[mat][rt][ct], 0, 0, 0);
                    acc[mat][rt][ct] = __builtin_amdgcn_mfma_f32_16x16x32_bf16(a_hi[rt][ks], bl, acc[mat][rt][ct], 0, 0, 0);
                }
            }
        }
    }

    const int dcol = lane & 15;
    const int rbase = (lane >> 4) * 4;
    float di[2][4];
#pragma unroll
    for (int rt = 0; rt < 2; ++rt)
#pragma unroll
        for (int reg = 0; reg < 4; ++reg)
            di[rt][reg] = sdinv[lbase + rt * 16 + rbase + reg];

#pragma unroll
    for (int ct = 0; ct < 4; ++ct) {
        int d = ct * 16 + dcol;
        float bias = bc[d] + bs[d];
#pragma unroll
        for (int rt = 0; rt < 2; ++rt) {
#pragma unroll
            for (int reg = 0; reg < 4; ++reg) {
                int row = rt0 + rt * 16 + rbase + reg;
                if (row < n) {
                    float dv = di[rt][reg];
                    float zc = acc[0][rt][ct][reg];
                    ybf[(size_t)row * 64 + d] = f2bf_rne(zc * dv);
                    out[(size_t)row * 64 + d] = acc[1][rt][ct][reg] + bias + dv * dv * zc;
                }
            }
        }
    }
}

// per-bin gather v5: CSR in LDS; paired half-wave uint loads, 8-deep pipeline.
__global__ __launch_bounds__(512) void k_gather_bin4(
    const int* __restrict__ gcur, const unsigned int* __restrict__ records,
    const unsigned short* __restrict__ ybf, const float* __restrict__ dinv,
    float* __restrict__ out, int n)
{
    __shared__ unsigned int srec[CAPB];   // 10 KB
    __shared__ int slist[CAPB];           // 10 KB: y byte offsets grouped by node
    __shared__ int scnt[128];
    __shared__ int sinc[128];
    __shared__ int scur[128];

    const int b = blockIdx.x, t = threadIdx.x;
    int m = gcur[b]; if (m > CAPB) m = CAPB;

    if (t < 128) scnt[t] = 0;
    __syncthreads();

    for (int k = t; k < m; k += 512) {
        unsigned r = __builtin_nontemporal_load(&records[(size_t)b * CAPB + k]);
        srec[k] = r;
        atomicAdd(&scnt[r & 127u], 1);
    }
    __syncthreads();

    if (t < 128) sinc[t] = scnt[t];
    __syncthreads();
    for (int off = 1; off < 128; off <<= 1) {
        int v = 0;
        if (t < 128 && t >= off) v = sinc[t - off];
        __syncthreads();
        if (t < 128) sinc[t] += v;
        __syncthreads();
    }
    if (t < 128) scur[t] = sinc[t] - scnt[t];
    __syncthreads();

    for (int k = t; k < m; k += 512) {
        unsigned r = srec[k];
        int slot = atomicAdd(&scur[r & 127u], 1);
        slist[slot] = (int)(r & ~127u);   // row*128 = byte offset into ybf
    }
    __syncthreads();

    const int wave = t >> 6, lane = t & 63;
    const int h = lane >> 5;                       // half-wave id
    const char* ybl = (const char*)ybf + ((lane & 31) << 2);

    for (int i = wave; i < 128; i += 8) {
        int node = (b << 7) + i;
        if (node >= n) break;
        int cnt = scnt[i];
        if (cnt == 0) continue;
        int beg = sinc[i] - cnt;
        float ax0=0.f,ax1=0.f,ax2=0.f,ax3=0.f,ax4=0.f,ax5=0.f,ax6=0.f,ax7=0.f;
        float ay0=0.f,ay1=0.f,ay2=0.f,ay3=0.f,ay4=0.f,ay5=0.f,ay6=0.f,ay7=0.f;
        int k = 0;
        for (; k + 16 <= cnt; k += 16) {
            int o0 = slist[beg + k + 0  + h];
            int o1 = slist[beg + k + 2  + h];
            int o2 = slist[beg + k + 4  + h];
            int o3 = slist[beg + k + 6  + h];
            int o4 = slist[beg + k + 8  + h];
            int o5 = slist[beg + k + 10 + h];
            int o6 = slist[beg + k + 12 + h];
            int o7 = slist[beg + k + 14 + h];
            unsigned v0 = *(const unsigned*)(ybl + o0);
            unsigned v1 = *(const unsigned*)(ybl + o1);
            unsigned v2 = *(const unsigned*)(ybl + o2);
            unsigned v3 = *(const unsigned*)(ybl + o3);
            unsigned v4 = *(const unsigned*)(ybl + o4);
            unsigned v5 = *(const unsigned*)(ybl + o5);
            unsigned v6 = *(const unsigned*)(ybl + o6);
            unsigned v7 = *(const unsigned*)(ybl + o7);
            ax0 += bf2f((unsigned short)v0); ay0 += bf2f((unsigned short)(v0 >> 16));
            ax1 += bf2f((unsigned short)v1); ay1 += bf2f((unsigned short)(v1 >> 16));
            ax2 += bf2f((unsigned short)v2); ay2 += bf2f((unsigned short)(v2 >> 16));
            ax3 += bf2f((unsigned short)v3); ay3 += bf2f((unsigned short)(v3 >> 16));
            ax4 += bf2f((unsigned short)v4); ay4 += bf2f((unsigned short)(v4 >> 16));
            ax5 += bf2f((unsigned short)v5); ay5 += bf2f((unsigned short)(v5 >> 16));
            ax6 += bf2f((unsigned short)v6); ay6 += bf2f((unsigned short)(v6 >> 16));
            ax7 += bf2f((unsigned short)v7); ay7 += bf2f((unsigned short)(v7 >> 16));
        }
        for (; k + 2 <= cnt; k += 2) {
            int o = slist[beg + k + h];
            unsigned v = *(const unsigned*)(ybl + o);
            ax0 += bf2f((unsigned short)v);
            ay0 += bf2f((unsigned short)(v >> 16));
        }
        if (k < cnt && h == 0) {
            int o = slist[beg + k];
            unsigned v = *(const unsigned*)(ybl + o);
            ax0 += bf2f((unsigned short)v);
            ay0 += bf2f((unsigned short)(v >> 16));
        }
        float sx = ((ax0+ax1)+(ax2+ax3)) + ((ax4+ax5)+(ax6+ax7));
        float sy = ((ay0+ay1)+(ay2+ay3)) + ((ay4+ay5)+(ay6+ay7));
        sx += __shfl_down(sx, 32);
        sy += __shfl_down(sy, 32);
        if (h == 0) {
            float dv = dinv[node];
            float* op = out + (size_t)node * 64 + ((lane & 31) << 1);
            float p0 = __builtin_nontemporal_load(op);
            float p1 = __builtin_nontemporal_load(op + 1);
            __builtin_nontemporal_store(p0 + dv * sx, op);
            __builtin_nontemporal_store(p1 + dv * sy, op + 1);
        }
    }
}

// overflow edges ((row,col) pairs): atomic fallback, after gather (bf16 y)
__global__ void k_ovf2(const int* __restrict__ ovfc, const int* __restrict__ ovf,
                       const float* __restrict__ dinv, const unsigned short* __restrict__ ybf,
                       float* __restrict__ out) {
    int m = *ovfc;
    long long total = (long long)m * 64;
    for (long long idx = blockIdx.x * blockDim.x + threadIdx.x; idx < total;
         idx += (long long)gridDim.x * blockDim.x) {
        int q = (int)(idx >> 6);
        int j = (int)(idx & 63);
        int r = ovf[2 * q], c = ovf[2 * q + 1];
        float s = dinv[c];
        float v = bf2f(ybf[(size_t)r * 64 + j]);
        unsafeAtomicAdd(out + (size_t)c * 64 + j, s * v);
    }
}

// ===================== padded-bucket fallback (round-3 proven) =====================

__global__ void k_init(int* __restrict__ cnt, int* __restrict__ ovf_cnt, int n) {
    int i = blockIdx.x * blockDim.x + threadIdx.x;
    if (i < n) cnt[i] = 0;
    if (i == 0) *ovf_cnt = 0;
}

__global__ void k_fill_pad(const int* __restrict__ row, const int* __restrict__ col,
                           int* __restrict__ cnt, int* __restrict__ bucket,
                           int* __restrict__ ovf, int* __restrict__ ovf_cnt, int e) {
    int i = blockIdx.x * blockDim.x + threadIdx.x;
    if (i >= e) return;
    int c = col[i];
    int p = atomicAdd(&cnt[c], 1);
    if (p < CAP) bucket[(size_t)c * CAP + p] = row[i];
    else { int q = atomicAdd(ovf_cnt, 1); ovf[q] = i; }
}

__global__ __launch_bounds__(256) void k_gemm(
    const float* __restrict__ x, const float* __restrict__ Wc,
    const float* __restrict__ bc, const float* __restrict__ Ws,
    const float* __restrict__ bs, const int* __restrict__ deg, int add,
    float* __restrict__ dinv, float* __restrict__ y,
    float* __restrict__ out, int n)
{
    __shared__ __align__(16) float sWc[64 * 64];
    __shared__ __align__(16) float sWs[64 * 64];
    __shared__ __align__(16) float sx[64 * 64];
    const int t = threadIdx.x;

    for (int i = t; i < 1024; i += 256) {
        ((float4*)sWc)[i] = ((const float4*)Wc)[i];
        ((float4*)sWs)[i] = ((const float4*)Ws)[i];
    }
    const int row0 = blockIdx.x * 64;
    int nrows = n - row0; if (nrows > 64) nrows = 64;
    for (int i = t; i < nrows * 16; i += 256) {
        ((float4*)sx)[i] = ((const float4*)(x + (size_t)row0 * 64))[i];
    }
    __syncthreads();

    const int d = t & 63;
    const int g = t >> 6;

    float wcr[64], wsr[64];
#pragma unroll
    for (int k = 0; k < 64; ++k) { wcr[k] = sWc[k * 64 + d]; wsr[k] = sWs[k * 64 + d]; }

    const float bcd = bc[d], bsd = bs[d];

    for (int rr = g * 16; rr < (g + 1) * 16; ++rr) {
        if (rr >= nrows) break;
        float accC = 0.f, accS = 0.f;
        const float4* xv4 = (const float4*)(sx + rr * 64);
#pragma unroll
        for (int q = 0; q < 16; ++q) {
            float4 xv = xv4[q];
            accC += xv.x*wcr[4*q+0] + xv.y*wcr[4*q+1] + xv.z*wcr[4*q+2] + xv.w*wcr[4*q+3];
            accS += xv.x*wsr[4*q+0] + xv.y*wsr[4*q+1] + xv.z*wsr[4*q+2] + xv.w*wsr[4*q+3];
        }
        const int r = row0 + rr;
        const float di = rsqrtf((float)(deg[r] + add));
        if (d == 0) dinv[r] = di;
        const float yv = accC * di;
        y[(size_t)r * 64 + d] = yv;
        out[(size_t)r * 64 + d] = accS + bsd + bcd + di * yv;
    }
}

__global__ __launch_bounds__(256) void k_gather_pad(
    const int* __restrict__ cnt, const int* __restrict__ bucket,
    const float* __restrict__ y, float* __restrict__ out, int n)
{
    const int node = blockIdx.x * 4 + (threadIdx.x >> 6);
    if (node >= n) return;
    const int lane = threadIdx.x & 63;
    int m = cnt[node];
    const float di = rsqrtf((float)(m + 1));
    if (m > CAP) m = CAP;
    if (m == 0) return;

    int rl = (lane < m) ? bucket[(size_t)node * CAP + lane] : 0;

    float a0=0.f,a1=0.f,a2=0.f,a3=0.f,a4=0.f,a5=0.f,a6=0.f,a7=0.f;
    int k = 0;
    for (; k + 8 <= m; k += 8) {
        int r0=__shfl(rl,k+0), r1=__shfl(rl,k+1), r2=__shfl(rl,k+2), r3=__shfl(rl,k+3);
        int r4=__shfl(rl,k+4), r5=__shfl(rl,k+5), r6=__shfl(rl,k+6), r7=__shfl(rl,k+7);
        a0 += y[(size_t)r0*64 + lane];
        a1 += y[(size_t)r1*64 + lane];
        a2 += y[(size_t)r2*64 + lane];
        a3 += y[(size_t)r3*64 + lane];
        a4 += y[(size_t)r4*64 + lane];
        a5 += y[(size_t)r5*64 + lane];
        a6 += y[(size_t)r6*64 + lane];
        a7 += y[(size_t)r7*64 + lane];
    }
    for (; k + 2 <= m; k += 2) {
        int r0=__shfl(rl,k+0), r1=__shfl(rl,k+1);
        a0 += y[(size_t)r0*64 + lane];
        a1 += y[(size_t)r1*64 + lane];
    }
    if (k < m) { int r0=__shfl(rl,k); a0 += y[(size_t)r0*64 + lane]; }

    float acc = ((a0+a1)+(a2+a3)) + ((a4+a5)+(a6+a7));
    out[(size_t)node*64 + lane] += di * acc;
}

__global__ void k_ovf_idx(const int* __restrict__ ovf_cnt, const int* __restrict__ ovf,
                          const int* __restrict__ row, const int* __restrict__ col,
                          const float* __restrict__ dinv, const float* __restrict__ y,
                          float* __restrict__ out) {
    int m = *ovf_cnt;
    long long total = (long long)m * 16;
    for (long long idx = blockIdx.x*blockDim.x+threadIdx.x; idx < total;
         idx += (long long)gridDim.x*blockDim.x) {
        int ei = ovf[idx >> 4];
        int j = (int)(idx & 15);
        int r = row[ei], c = col[ei];
        float s = dinv[c];
        float4 v = ((const float4*)y)[(size_t)r*16 + j];
        float* o = out + (size_t)c*64 + (j<<2);
        unsafeAtomicAdd(o+0, s*v.x);
        unsafeAtomicAdd(o+1, s*v.y);
        unsafeAtomicAdd(o+2, s*v.z);
        unsafeAtomicAdd(o+3, s*v.w);
    }
}

__global__ void k_deg_init(int* __restrict__ deg, int n) {
    int i = blockIdx.x * blockDim.x + threadIdx.x;
    if (i < n) deg[i] = 1;
}

__global__ void k_deg_count(const int* __restrict__ col, int* __restrict__ deg, int e) {
    int i = blockIdx.x * blockDim.x + threadIdx.x;
    if (i < e) atomicAdd(&deg[col[i]], 1);
}

__global__ __launch_bounds__(256) void k_scatter(
    const int* __restrict__ row, const int* __restrict__ col,
    const float* __restrict__ dinv, const float* __restrict__ y,
    float* __restrict__ out, int e)
{
    int idx = blockIdx.x * blockDim.x + threadIdx.x;
    int eidx = idx >> 4;
    if (eidx >= e) return;
    int j = idx & 15;
    int r = row[eidx];
    int c = col[eidx];
    float s = dinv[c];
    float4 v = ((const float4*)y)[(size_t)r * 16 + j];
    float* o = out + (size_t)c * 64 + (j << 2);
    unsafeAtomicAdd(o + 0, s * v.x);
    unsafeAtomicAdd(o + 1, s * v.y);
    unsafeAtomicAdd(o + 2, s * v.z);
    unsafeAtomicAdd(o + 3, s * v.w);
}

extern "C" void kernel_launch(void* const* d_in, const int* in_sizes, int n_in,
                              void* d_out, int out_size, void* d_ws, size_t ws_size,
                              hipStream_t stream) {
    const float* x  = (const float*)d_in[0];
    const int*   ei = (const int*)d_in[1];
    const float* Wc = (const float*)d_in[2];
    const float* bc = (const float*)d_in[3];
    const float* Ws = (const float*)d_in[4];
    const float* bs = (const float*)d_in[5];
    float* out = (float*)d_out;

    const int n = in_sizes[0] / 64;
    const int e = in_sizes[1] / 2;
    const int* rowi = ei;
    const int* coli = ei + e;

    auto align = [](size_t v) { return (v + 255) & ~(size_t)255; };
    char* ws = (char*)d_ws;
    const int nbins = (n + 127) >> 7;

    // ---- binned layout (y is bf16: n*128 bytes) ----
    size_t m_dinv = 0;
    size_t m_y    = align(m_dinv + (size_t)n * 4);
    size_t m_gcur = align(m_y    + (size_t)n * 128);
    size_t m_rec  = align(m_gcur + (size_t)nbins * 4);
    size_t m_dov  = align(m_rec  + (size_t)nbins * CAPB * 4);
    size_t m_ovf  = align(m_dov  + (size_t)n * 4);
    size_t m_ovfc = align(m_ovf  + (size_t)e * 8);
    size_t m_bfr  = align(m_ovfc + 256);
    size_t m_tot  = m_bfr + 32768;

    // ---- padded-bucket layout ----
    size_t p_cnt  = 0;
    size_t p_dinv = align(p_cnt  + (size_t)n * 4);
    size_t p_y    = align(p_dinv + (size_t)n * 4);
    size_t p_bkt  = align(p_y    + (size_t)n * 256);
    size_t p_ovf  = align(p_bkt  + (size_t)n * CAP * 4);
    size_t p_ovfc = align(p_ovf  + (size_t)e * 4);
    size_t p_tot  = p_ovfc + 256;

    if (nbins <= NBINS_MAX && m_tot <= ws_size) {
        float* dinv = (float*)(ws + m_dinv);
        unsigned short* ybf = (unsigned short*)(ws + m_y);
        int*   gcur = (int*)(ws + m_gcur);
        unsigned int* rec = (unsigned int*)(ws + m_rec);
        int*   dov  = (int*)(ws + m_dov);
        int*   ovf  = (int*)(ws + m_ovf);
        int*   ovfc = (int*)(ws + m_ovfc);
        unsigned short* bfrag = (unsigned short*)(ws + m_bfr);

        int zmax = (n > nbins) ? n : nbins;
        k_zero2<<<(zmax + 255) / 256 + 1, 256, 0, stream>>>(gcur, nbins, dov, n, ovfc,
                                                            Wc, Ws, bfrag);
        k_bin<<<(e + CHUNK - 1) / CHUNK, 512, 0, stream>>>(rowi, coli, e, nbins,
                                                           gcur, rec, dov, ovf, ovfc);
        k_gemm6<<<nbins, 256, 0, stream>>>(x, bfrag, bc, bs, rec, gcur, dov,
                                           dinv, ybf, out, n);
        k_gather_bin4<<<nbins, 512, 0, stream>>>(gcur, rec, ybf, dinv, out, n);
        k_ovf2<<<64, 256, 0, stream>>>(ovfc, ovf, dinv, ybf, out);
    } else if (p_tot <= ws_size) {
        int*   cnt    = (int*)(ws + p_cnt);
        float* dinv   = (float*)(ws + p_dinv);
        float* y      = (float*)(ws + p_y);
        int*   bucket = (int*)(ws + p_bkt);
        int*   ovf    = (int*)(ws + p_ovf);
        int*   ovfc   = (int*)(ws + p_ovfc);

        k_init<<<(n + 255) / 256, 256, 0, stream>>>(cnt, ovfc, n);
        k_fill_pad<<<(e + 255) / 256, 256, 0, stream>>>(rowi, coli, cnt, bucket, ovf, ovfc, e);
        k_gemm<<<(n + 63) / 64, 256, 0, stream>>>(x, Wc, bc, Ws, bs, cnt, 1, dinv, y, out, n);
        k_gather_pad<<<(n + 3) / 4, 256, 0, stream>>>(cnt, bucket, y, out, n);
        k_ovf_idx<<<64, 256, 0, stream>>>(ovfc, ovf, rowi, coli, dinv, y, out);
    } else {
        size_t a_deg  = 0;
        size_t a_dinv = align(a_deg  + (size_t)n * 4);
        size_t a_y    = align(a_dinv + (size_t)n * 4);
        int*   deg  = (int*)(ws + a_deg);
        float* dinv = (float*)(ws + a_dinv);
        float* y    = (float*)(ws + a_y);
        k_deg_init<<<(n + 255) / 256, 256, 0, stream>>>(deg, n);
        k_deg_count<<<(e + 255) / 256, 256, 0, stream>>>(coli, deg, e);
        k_gemm<<<(n + 63) / 64, 256, 0, stream>>>(x, Wc, bc, Ws, bs, deg, 0, dinv, y, out, n);
        long long tot = (long long)e * 16;
        k_scatter<<<(int)((tot + 255) / 256), 256, 0, stream>>>(rowi, coli, dinv, y, out, e);
    }
}